// Round 8
// baseline (232.813 us; speedup 1.0000x reference)
//
#include <hip/hip_runtime.h>
#include <hip/hip_bf16.h>

#define B_ROWS 8192
#define D_DIM  2048
#define C_DIM  1000
#define C_PAD  1024

#define EPS32   1.1920928955078125e-07f
// GAMMA = 1/exp(100) ~ 3.7e-44. GAMMA*rex ~ 1e-40 << ulp(h3~6.9) ~ 4.8e-7,
// so loss == mean(h3) exactly in fp32. rex pipeline deleted (round 5).
// Round 12: rownorm 4 rows/wave ILP-16, finalize 1024-thr — total 232.5us (best).
// Round 13: gemm_bt was grid-limited (512 blocks = 2/CU, Occupancy 20%, MfmaUtil
// 24%, FETCH 33MB = cache-served -> latency-bound not BW-bound). Retile 128x128
// -> 128x64: grid (64,16)=1024 blocks = 4/CU, LDS 24KB. fuse_z: 16B stores
// (2 contiguous pairs/thread) — final probe before declaring its ~55us a plateau.

typedef __attribute__((ext_vector_type(8))) short short8;   // 8 bf16 = 4 VGPRs
typedef __attribute__((ext_vector_type(4))) float f32x4;    // MFMA accumulator

#define GLOAD_LDS16(gptr, lptr) \
  __builtin_amdgcn_global_load_lds((const __attribute__((address_space(1))) void*)(gptr), \
                                   (__attribute__((address_space(3))) void*)(lptr), 16, 0, 0)

__device__ inline unsigned short f2bf(float x) {
  union { __hip_bfloat16 b; unsigned short u; } cv;
  cv.b = __float2bfloat16(x);
  return cv.u;
}

__device__ inline float wave_red(float v) {
#pragma unroll
  for (int off = 32; off > 0; off >>= 1) v += __shfl_down(v, off, 64);
  return v;
}

// ---- B+P merged:
//   blocks [0,8192):      z_bf = bf16(feature+eps); thread owns 2 CONTIGUOUS
//                         float4-pairs -> 4x16B loads, 1x16B store (was 2x8B).
//   blocks [8192,9216):   cast cls_w [1000,2048] -> bf16 padded [1024,2048].
#define ZBLK 8192
__global__ __launch_bounds__(256) void fuse_z(const float4* __restrict__ f4,
                                              const float4* __restrict__ e4,
                                              uint4* __restrict__ z4,
                                              const float* __restrict__ cls_w,
                                              __hip_bfloat16* __restrict__ clsw_bf) {
  int bid = blockIdx.x;
  if (bid < ZBLK) {
    int t = bid * 256 + threadIdx.x;
    int i0 = t * 2;
    float4 f0 = f4[i0], f1 = f4[i0 + 1];
    float4 e0 = e4[i0], e1 = e4[i0 + 1];
    union { unsigned short u[8]; uint4 v; } pz;
    pz.u[0] = f2bf(f0.x + e0.x);
    pz.u[1] = f2bf(f0.y + e0.y);
    pz.u[2] = f2bf(f0.z + e0.z);
    pz.u[3] = f2bf(f0.w + e0.w);
    pz.u[4] = f2bf(f1.x + e1.x);
    pz.u[5] = f2bf(f1.y + e1.y);
    pz.u[6] = f2bf(f1.z + e1.z);
    pz.u[7] = f2bf(f1.w + e1.w);
    z4[t] = pz.v;
  } else {
    int j = ((bid - ZBLK) * 256 + threadIdx.x) * 8;   // elem idx in [1024][2048]
    int row = j >> 11;
    int col = j & 2047;
    union { unsigned short u[8]; uint4 v; } pk;
    if (row < C_DIM) {
      const float* src = cls_w + (size_t)row * D_DIM + col;
#pragma unroll
      for (int i2 = 0; i2 < 8; ++i2) pk.u[i2] = f2bf(src[i2]);
    } else {
#pragma unroll
      for (int i2 = 0; i2 < 8; ++i2) pk.u[i2] = 0;
    }
    *(uint4*)((unsigned short*)clsw_bf + j) = pk.v;
  }
}

// ---- C: probs_raw = z @ cls_w^T + cls_b
// Round 13: BM=128, BN=64, BK=64. Grid (64,16)=1024 blocks (4/CU; was 512=2/CU).
// 4 waves as 2x2, each 64x32 output (acc[4][2]). LDS 24KB, XOR-swizzled:
// 16B chunk (row, cc) at slot row*8 + (cc ^ (row&7)).
__global__ __launch_bounds__(256) void gemm_bt(const __hip_bfloat16* __restrict__ A,
                                               const __hip_bfloat16* __restrict__ Bt,
                                               const float* __restrict__ cls_b,
                                               float* __restrict__ out) {
  __shared__ __align__(16) __hip_bfloat16 sA[128 * 64];   // 16 KB
  __shared__ __align__(16) __hip_bfloat16 sB[64 * 64];    //  8 KB
  const int tid = threadIdx.x;
  const int m0 = blockIdx.x * 128;
  const int n0 = blockIdx.y * 64;
  const int w = tid >> 6, lane = tid & 63;
  const int wm = (w & 1) * 64, wn = (w >> 1) * 32;
  const int l15 = lane & 15, quad = lane >> 4;

  f32x4 acc[4][2] = {};

  for (int k0 = 0; k0 < D_DIM; k0 += 64) {
#pragma unroll
    for (int i = 0; i < 4; ++i) {
      int j = i * 256 + tid;          // A: 1024 chunks of 16B (128 rows x 8)
      int row = j >> 3;
      int cc = (j & 7) ^ (row & 7);   // inverse of the swizzle (XOR involution)
      GLOAD_LDS16(A + (size_t)(m0 + row) * D_DIM + k0 + cc * 8, &sA[j * 8]);
    }
#pragma unroll
    for (int i = 0; i < 2; ++i) {
      int j = i * 256 + tid;          // B: 512 chunks (64 rows x 8)
      int row = j >> 3;
      int cc = (j & 7) ^ (row & 7);
      GLOAD_LDS16(Bt + (size_t)(n0 + row) * D_DIM + k0 + cc * 8, &sB[j * 8]);
    }
    __syncthreads();
#pragma unroll
    for (int kk = 0; kk < 64; kk += 32) {
      const int ccr = (kk >> 3) + quad;   // which 8-elem chunk along K
      short8 af[4], bfr[2];
#pragma unroll
      for (int i = 0; i < 4; ++i) {
        int r = wm + i * 16 + l15;
        af[i] = *(const short8*)&sA[(r * 8 + (ccr ^ (r & 7))) * 8];
      }
#pragma unroll
      for (int jn = 0; jn < 2; ++jn) {
        int r = wn + jn * 16 + l15;
        bfr[jn] = *(const short8*)&sB[(r * 8 + (ccr ^ (r & 7))) * 8];
      }
#pragma unroll
      for (int i = 0; i < 4; ++i)
#pragma unroll
        for (int jn = 0; jn < 2; ++jn)
          acc[i][jn] = __builtin_amdgcn_mfma_f32_16x16x32_bf16(af[i], bfr[jn], acc[i][jn], 0, 0, 0);
    }
    __syncthreads();
  }

  // epilogue: C/D layout col=lane&15, row=quad*4+reg  (m89-verified)
#pragma unroll
  for (int i = 0; i < 4; ++i) {
    int row = m0 + wm + i * 16 + quad * 4;
#pragma unroll
    for (int jn = 0; jn < 2; ++jn) {
      int col = n0 + wn + jn * 16 + l15;
      if (col < C_DIM) {
        float bias = cls_b[col];
#pragma unroll
        for (int r = 0; r < 4; ++r)
          out[(size_t)(row + r) * C_DIM + col] = acc[i][jn][r] + bias;
      }
    }
  }
}

// ---- D: per-row normalize+clamp+log, 4 rows per wave (round 12, proven).
__global__ __launch_bounds__(256) void rownorm(float* __restrict__ out,
                                               const int* __restrict__ target,
                                               float* __restrict__ rowloss) {
  const int wv = threadIdx.x >> 6, lane = threadIdx.x & 63;
  const int r0 = blockIdx.x * 16 + wv * 4;

  float v[4][16];
#pragma unroll
  for (int rr = 0; rr < 4; ++rr) {
    const float* row = out + (size_t)(r0 + rr) * C_DIM;
#pragma unroll
    for (int k = 0; k < 4; ++k) {
      int c = k * 256 + lane * 4;
      if (c + 3 < C_DIM) {
        float4 f = *(const float4*)(row + c);
        v[rr][k * 4 + 0] = f.x; v[rr][k * 4 + 1] = f.y;
        v[rr][k * 4 + 2] = f.z; v[rr][k * 4 + 3] = f.w;
      } else {
#pragma unroll
        for (int i = 0; i < 4; ++i) v[rr][k * 4 + i] = (c + i < C_DIM) ? row[c + i] : 0.f;
      }
    }
  }

  float s[4];
#pragma unroll
  for (int rr = 0; rr < 4; ++rr) {
    float a = 0.f;
#pragma unroll
    for (int k = 0; k < 16; ++k) a += v[rr][k];
    s[rr] = a;
  }
#pragma unroll
  for (int rr = 0; rr < 4; ++rr) {
#pragma unroll
    for (int off = 32; off > 0; off >>= 1) s[rr] += __shfl_down(s[rr], off, 64);
    s[rr] = __shfl(s[rr], 0, 64);
  }

  int tg[4];
#pragma unroll
  for (int rr = 0; rr < 4; ++rr) tg[rr] = target[r0 + rr];

#pragma unroll
  for (int rr = 0; rr < 4; ++rr) {
    float inv = 1.0f / s[rr];
    float* row = out + (size_t)(r0 + rr) * C_DIM;
#pragma unroll
    for (int k = 0; k < 4; ++k) {
      int c = k * 256 + lane * 4;
      float lg[4];
#pragma unroll
      for (int i = 0; i < 4; ++i) {
        float p = v[rr][k * 4 + i] * inv;
        p = fminf(fmaxf(p, EPS32), 1.0f - EPS32);
        lg[i] = __logf(p);
        if (c + i == tg[rr]) rowloss[r0 + rr] = -lg[i];
      }
      if (c + 3 < C_DIM) {
        *(float4*)(row + c) = make_float4(lg[0], lg[1], lg[2], lg[3]);
      } else {
#pragma unroll
        for (int i = 0; i < 4; ++i) if (c + i < C_DIM) row[c + i] = lg[i];
      }
    }
  }
}

// ---- E: loss = mean(rowloss). One 1024-thread block, ILP-8, plain store.
__global__ __launch_bounds__(1024) void finalize(const float* __restrict__ rowloss,
                                                 float* __restrict__ out_loss) {
  int tid = threadIdx.x;
  float a[8];
#pragma unroll
  for (int j = 0; j < 8; ++j) a[j] = rowloss[tid + j * 1024];
  float s = 0.f;
#pragma unroll
  for (int j = 0; j < 8; ++j) s += a[j];
  s = wave_red(s);
  __shared__ float sm[16];
  if ((tid & 63) == 0) sm[tid >> 6] = s;
  __syncthreads();
  if (tid == 0) {
    float t = 0.f;
#pragma unroll
    for (int k = 0; k < 16; ++k) t += sm[k];
    out_loss[0] = t * (1.0f / B_ROWS);
  }
}

extern "C" void kernel_launch(void* const* d_in, const int* in_sizes, int n_in,
                              void* d_out, int out_size, void* d_ws, size_t ws_size,
                              hipStream_t stream) {
  const float* feature = (const float*)d_in[0];
  const float* cls_w   = (const float*)d_in[3];
  const float* cls_b   = (const float*)d_in[4];
  const float* eps     = (const float*)d_in[5];
  const int*   target  = (const int*)d_in[6];
  float* out = (float*)d_out;
  float* out_loss = out + (size_t)B_ROWS * C_DIM;

  char* ws = (char*)d_ws;
  __hip_bfloat16* z_bf    = (__hip_bfloat16*)ws;                // 33554432 B
  __hip_bfloat16* clsw_bf = (__hip_bfloat16*)(ws + 33554432);   //  4194304 B
  float*          rowloss = (float*)(ws + 33554432 + 4194304);  //    32768 B

  fuse_z<<<dim3(ZBLK + 1024), 256, 0, stream>>>((const float4*)feature, (const float4*)eps,
                                                (uint4*)z_bf, cls_w, clsw_bf);
  gemm_bt<<<dim3(B_ROWS / 128, C_PAD / 64), 256, 0, stream>>>(z_bf, clsw_bf, cls_b, out);
  rownorm<<<dim3(B_ROWS / 16), 256, 0, stream>>>(out, target, rowloss);
  finalize<<<dim3(1), 1024, 0, stream>>>(rowloss, out_loss);
}